// Round 5
// baseline (1739.588 us; speedup 1.0000x reference)
//
#include <hip/hip_runtime.h>
#include <math.h>

typedef _Float16 h2f __attribute__((ext_vector_type(2)));

__device__ __forceinline__ float fdot2f(h2f a, h2f b, float c) {
#if __has_builtin(__builtin_amdgcn_fdot2)
  return __builtin_amdgcn_fdot2(a, b, c, false);
#else
  return c + (float)a[0] * (float)b[0] + (float)a[1] * (float)b[1];
#endif
}

__device__ __forceinline__ h2f rl_h2f(float v, int lane) {
  union { float f; int i; } u;
  u.f = v;
  int s = __builtin_amdgcn_readlane(u.i, lane);
  union { int i; h2f h; } r;
  r.i = s;
  return r.h;
}

__device__ __forceinline__ float sigf(float x) {
  return __builtin_amdgcn_rcpf(1.f + __expf(-x));
}
__device__ __forceinline__ float tanh_fast(float x) {
  return 2.f * __builtin_amdgcn_rcpf(1.f + __expf(-2.f * x)) - 1.f;
}

__device__ __forceinline__ int clampi(int v, int lo, int hi) {
  return v < lo ? lo : (v > hi ? hi : v);
}

// ---------------------------------------------------------------------------
// Kernel A: per-token: ft gather + char conv (3,4,5) -> lstm_in[1024][450]
// ---------------------------------------------------------------------------
__global__ __launch_bounds__(64) void k_token(
    const float* __restrict__ fast_text, const float* __restrict__ char_table,
    const float* __restrict__ w3, const float* __restrict__ b3,
    const float* __restrict__ w4, const float* __restrict__ b4,
    const float* __restrict__ w5, const float* __restrict__ b5,
    const int* __restrict__ word_ids, const int* __restrict__ char_ids,
    float* __restrict__ lstm_in) {
  const int t = blockIdx.x;
  const int tid = threadIdx.x;
  __shared__ float ce[16][16];  // ce[l][ci]
  for (int i = tid; i < 256; i += 64) {
    int l = i >> 4, ci = i & 15;
    ce[l][ci] = char_table[char_ids[t * 16 + l] * 16 + ci];
  }
  __syncthreads();
  const int wid = word_ids[t];
  for (int d = tid; d < 300; d += 64)
    lstm_in[t * 450 + d] = fast_text[wid * 300 + d];
  const int f = tid;
  if (f < 50) {
    {
      float acc[14];
#pragma unroll
      for (int p = 0; p < 14; ++p) acc[p] = 0.f;
      for (int ci = 0; ci < 16; ++ci) {
#pragma unroll
        for (int kk = 0; kk < 3; ++kk) {
          float wv = w3[(f * 16 + ci) * 3 + kk];
#pragma unroll
          for (int p = 0; p < 14; ++p) acc[p] += ce[p + kk][ci] * wv;
        }
      }
      float m = acc[0];
#pragma unroll
      for (int p = 1; p < 14; ++p) m = fmaxf(m, acc[p]);
      lstm_in[t * 450 + 300 + f] = fmaxf(0.f, m + b3[f]);
    }
    {
      float acc[13];
#pragma unroll
      for (int p = 0; p < 13; ++p) acc[p] = 0.f;
      for (int ci = 0; ci < 16; ++ci) {
#pragma unroll
        for (int kk = 0; kk < 4; ++kk) {
          float wv = w4[(f * 16 + ci) * 4 + kk];
#pragma unroll
          for (int p = 0; p < 13; ++p) acc[p] += ce[p + kk][ci] * wv;
        }
      }
      float m = acc[0];
#pragma unroll
      for (int p = 1; p < 13; ++p) m = fmaxf(m, acc[p]);
      lstm_in[t * 450 + 350 + f] = fmaxf(0.f, m + b4[f]);
    }
    {
      float acc[12];
#pragma unroll
      for (int p = 0; p < 12; ++p) acc[p] = 0.f;
      for (int ci = 0; ci < 16; ++ci) {
#pragma unroll
        for (int kk = 0; kk < 5; ++kk) {
          float wv = w5[(f * 16 + ci) * 5 + kk];
#pragma unroll
          for (int p = 0; p < 12; ++p) acc[p] += ce[p + kk][ci] * wv;
        }
      }
      float m = acc[0];
#pragma unroll
      for (int p = 1; p < 12; ++p) m = fmaxf(m, acc[p]);
      lstm_in[t * 450 + 400 + f] = fmaxf(0.f, m + b5[f]);
    }
  }
}

// ---------------------------------------------------------------------------
// Generic fp32 GEMM: C[M][N] = A[M][K] @ W[N][K]^T (+ bias[N] if non-null)
// ---------------------------------------------------------------------------
__global__ __launch_bounds__(256) void gemm_nt(
    const float* __restrict__ A, const float* __restrict__ W,
    const float* __restrict__ bias, float* __restrict__ C,
    int M, int N, int K) {
  __shared__ float As[16][64];
  __shared__ float Ws[16][64];
  const int tid = threadIdx.x;
  const int tx = tid & 15, ty = tid >> 4;
  const int r0 = blockIdx.x * 64, c0 = blockIdx.y * 64;
  float acc[4][4] = {};
  for (int k0 = 0; k0 < K; k0 += 16) {
    for (int i = tid; i < 1024; i += 256) {
      int rr = i >> 4, kk = i & 15;
      int r = r0 + rr, k = k0 + kk;
      As[kk][rr] = (r < M && k < K) ? A[r * K + k] : 0.f;
      int c = c0 + rr;
      Ws[kk][rr] = (c < N && k < K) ? W[c * K + k] : 0.f;
    }
    __syncthreads();
#pragma unroll
    for (int kk = 0; kk < 16; ++kk) {
      const float4 av = *(const float4*)(&As[kk][ty * 4]);
      const float4 wv = *(const float4*)(&Ws[kk][tx * 4]);
      float a[4] = {av.x, av.y, av.z, av.w};
      float w[4] = {wv.x, wv.y, wv.z, wv.w};
#pragma unroll
      for (int i = 0; i < 4; ++i)
#pragma unroll
        for (int j = 0; j < 4; ++j) acc[i][j] += a[i] * w[j];
    }
    __syncthreads();
  }
#pragma unroll
  for (int i = 0; i < 4; ++i) {
    int r = r0 + ty * 4 + i;
    if (r >= M) continue;
#pragma unroll
    for (int j = 0; j < 4; ++j) {
      int c = c0 + tx * 4 + j;
      if (c < N) C[r * N + c] = acc[i][j] + (bias ? bias[c] : 0.f);
    }
  }
}

// ---------------------------------------------------------------------------
// Kernel C: LSTM recurrence, one block per direction.
// 640 threads, 600 active. Thread tid owns z-row (tid&3)*150 + (tid>>2);
// gate exchange via __shfl_xor within 4 adjacent lanes.
// Round-4 finding: h broadcast via 19 ds_read_b128/thread was LDS-throughput
// bound (190 LDS instr/step/CU ~= 2280 cy, matching 2180 cy/step observed).
// Now: per wave ONE ds_read_b128 (lanes 0..18 hold h packed f16, 4 h2f each),
// then v_readlane moves h through SGPRs (VALU, not LDS pipe) into the dot.
// ---------------------------------------------------------------------------
__attribute__((amdgpu_waves_per_eu(3, 3)))
__global__ __launch_bounds__(640) void k_lstm(
    const float* __restrict__ xprojF, const float* __restrict__ xprojB,
    const float* __restrict__ Wh_f, const float* __restrict__ Wh_b,
    float* __restrict__ keys) {
  const int dir = blockIdx.x;
  const float* __restrict__ xp = dir ? xprojB : xprojF;
  const float* __restrict__ Wh = dir ? Wh_b : Wh_f;
  const int tid = threadIdx.x;
  const int u = tid >> 2;   // hidden unit (valid < 150)
  const int g = tid & 3;    // gate: 0=i 1=f 2=g 3=o
  const int row = g * 150 + u;
  const bool act = (tid < 600);
  const int lane = tid & 63;
  const int hq_idx = lane < 19 ? lane : 18;  // float4 slot this lane stages

  __shared__ alignas(16) h2f hbuf[2][76];  // h packed f16, 150 + 2 pad

  h2f w[75];
  if (act) {
    const float2* Wr = (const float2*)(Wh + row * 150);
#pragma unroll
    for (int kk = 0; kk < 75; ++kk) {
      float2 a = Wr[kk];
      h2f v;
      v[0] = (_Float16)a.x;
      v[1] = (_Float16)a.y;
      w[kk] = v;
    }
  }
  for (int i = tid; i < 152; i += 640) {
    h2f z;
    z[0] = (_Float16)0.f;
    z[1] = (_Float16)0.f;
    hbuf[i / 76][i % 76] = z;
  }
  float c = 0.f;
  float xv = act ? xp[(dir ? 1023 : 0) * 600 + row] : 0.f;
  __syncthreads();

  int cur = 0;
  for (int step = 0; step < 1024; ++step) {
    const int t = dir ? (1023 - step) : step;
    const int tn = dir ? (t > 0 ? t - 1 : 0) : (t < 1023 ? t + 1 : 1023);
    float z = 0.f;
    // every wave stages h: lane l (<19) holds h2f[4l..4l+3]
    const float4 hq = ((const float4*)hbuf[cur])[hq_idx];
    if (act) {
      // prefetch next step's xp (hidden under the dot chain)
      const float xv_next = xp[tn * 600 + row];
      float a0 = 0.f, a1 = 0.f, a2 = 0.f, a3 = 0.f;
#pragma unroll
      for (int q = 0; q < 18; ++q) {
        a0 = fdot2f(w[4 * q + 0], rl_h2f(hq.x, q), a0);
        a1 = fdot2f(w[4 * q + 1], rl_h2f(hq.y, q), a1);
        a2 = fdot2f(w[4 * q + 2], rl_h2f(hq.z, q), a2);
        a3 = fdot2f(w[4 * q + 3], rl_h2f(hq.w, q), a3);
      }
      a0 = fdot2f(w[72], rl_h2f(hq.x, 18), a0);
      a1 = fdot2f(w[73], rl_h2f(hq.y, 18), a1);
      a2 = fdot2f(w[74], rl_h2f(hq.z, 18), a2);
      z = (a0 + a1) + (a2 + a3) + xv;
      xv = xv_next;
    }
    // nonlinearity: sigmoid for i,f,o; tanh for g (tanh(z)=2*sig(2z)-1)
    float val = 0.f;
    if (act) {
      const float zz = (g == 2) ? 2.f * z : z;
      const float s = sigf(zz);
      val = (g == 2) ? (2.f * s - 1.f) : s;
    }
    const float v1 = __shfl_xor(val, 1);  // lane g0: f   | lane g2: o
    const float gv = __shfl_xor(val, 2);  // lane g0: g
    const float ov = __shfl_xor(v1, 2);   // lane g0: o
    if (act && g == 0) {
      c = v1 * c + val * gv;
      const float h = ov * tanh_fast(c);
      keys[t * 300 + dir * 150 + u] = h;
      ((_Float16*)hbuf[cur ^ 1])[u] = (_Float16)h;
    }
    cur ^= 1;
    __syncthreads();
  }
}

// ---------------------------------------------------------------------------
// Kernel D: span scorer -> enc[512][1000]
// ---------------------------------------------------------------------------
__global__ __launch_bounds__(320) void k_span(
    const float* __restrict__ keys, const float* __restrict__ lstm_in,
    const float* __restrict__ W1, const float* __restrict__ b1,
    const float* __restrict__ W2, const float* __restrict__ b2,
    const float* __restrict__ w_out, const float* __restrict__ feat_table,
    const int* __restrict__ espans, float* __restrict__ enc) {
  const int e = blockIdx.x;
  const int tid = threadIdx.x;
  const int s = espans[e * 4 + 0];
  const int en = espans[e * 4 + 1];
  const int f0 = espans[e * 4 + 2];
  const int f1 = espans[e * 4 + 3];

  __shared__ float ksh[10][300];
  __shared__ float hsh[10][152];
  __shared__ float h2sh[10][152];
  __shared__ float att[10];
  __shared__ float scl[2];

  for (int i = tid; i < 3000; i += 320) {
    int p = i / 300, d = i % 300;
    int row = clampi(s + p, 0, 1023);
    ksh[p][d] = keys[row * 300 + d];
  }
  __syncthreads();

  if (tid < 152) {
    int jj = tid;
    if (jj < 150) {
      float acc[10];
#pragma unroll
      for (int p = 0; p < 10; ++p) acc[p] = b1[jj];
      for (int k = 0; k < 300; k += 4) {
        float w0 = W1[(k + 0) * 150 + jj];
        float w1 = W1[(k + 1) * 150 + jj];
        float w2 = W1[(k + 2) * 150 + jj];
        float w3 = W1[(k + 3) * 150 + jj];
#pragma unroll
        for (int p = 0; p < 10; ++p) {
          const float4 kv = *(const float4*)(&ksh[p][k]);
          acc[p] += kv.x * w0 + kv.y * w1 + kv.z * w2 + kv.w * w3;
        }
      }
#pragma unroll
      for (int p = 0; p < 10; ++p) hsh[p][jj] = fmaxf(acc[p], 0.f);
    } else {
#pragma unroll
      for (int p = 0; p < 10; ++p) hsh[p][jj] = 0.f;
    }
  }
  __syncthreads();

  if (tid < 150) {
    int jj = tid;
    float acc[10];
#pragma unroll
    for (int p = 0; p < 10; ++p) acc[p] = b2[jj];
    for (int k = 0; k < 152; k += 4) {
      float w0 = (k + 0 < 150) ? W2[(k + 0) * 150 + jj] : 0.f;
      float w1 = (k + 1 < 150) ? W2[(k + 1) * 150 + jj] : 0.f;
      float w2 = (k + 2 < 150) ? W2[(k + 2) * 150 + jj] : 0.f;
      float w3 = (k + 3 < 150) ? W2[(k + 3) * 150 + jj] : 0.f;
#pragma unroll
      for (int p = 0; p < 10; ++p) {
        const float4 hv = *(const float4*)(&hsh[p][k]);
        acc[p] += hv.x * w0 + hv.y * w1 + hv.z * w2 + hv.w * w3;
      }
    }
#pragma unroll
    for (int p = 0; p < 10; ++p) h2sh[p][jj] = fmaxf(acc[p], 0.f);
  }
  __syncthreads();

  if (tid < 10) {
    float lg = -1e30f;
    if (tid < en - s) {
      float d = 0.f;
      for (int k = 0; k < 150; ++k) d += h2sh[tid][k] * w_out[k];
      lg = d;
    }
    att[tid] = lg;
  }
  if (tid >= 64 && tid < 66) {
    int r = tid - 64;
    int fi = (r == 0) ? f0 : f1;
    float nsq = 0.f;
    for (int k = 0; k < 50; ++k) {
      float v = feat_table[fi * 50 + k];
      nsq += v * v;
    }
    float n = sqrtf(nsq);
    scl[r] = fminf(1.f, 1.f / fmaxf(n, 1e-7f));
  }
  __syncthreads();

  if (tid == 0) {
    float m = -1e30f;
    for (int p = 0; p < 10; ++p) m = fmaxf(m, att[p]);
    float ex[10];
    float ssum = 0.f;
    for (int p = 0; p < 10; ++p) {
      ex[p] = expf(att[p] - m);
      ssum += ex[p];
    }
    for (int p = 0; p < 10; ++p) att[p] = ex[p] / ssum;
  }
  __syncthreads();

  if (tid < 300) {
    int d = tid;
    float xf = keys[s * 300 + d];
    float xl = keys[(en - 1) * 300 + d];
    float xh = 0.f;
#pragma unroll
    for (int p = 0; p < 10; ++p) {
      int row = clampi(s + p, 0, 1023);
      xh += att[p] * lstm_in[row * 450 + d];
    }
    enc[e * 1000 + d] = xf;
    enc[e * 1000 + 300 + d] = xl;
    enc[e * 1000 + 600 + d] = xh;
  }
  if (tid < 100) {
    int r = tid / 50, cc = tid % 50;
    int fi = (r == 0) ? f0 : f1;
    enc[e * 1000 + 900 + tid] = feat_table[fi * 50 + cc] * scl[r];
  }
}

// ---------------------------------------------------------------------------
// Kernel E: small = enc @ affine_W + affine_b   (4 spans per block)
// ---------------------------------------------------------------------------
__global__ __launch_bounds__(320) void k_affine(
    const float* __restrict__ enc, const float* __restrict__ W,
    const float* __restrict__ bias, float* __restrict__ small) {
  const int e0 = blockIdx.x * 4;
  const int tid = threadIdx.x;
  __shared__ float es[4][1000];
  for (int i = tid; i < 4000; i += 320) es[i / 1000][i % 1000] = enc[e0 * 1000 + i];
  __syncthreads();
  if (tid < 300) {
    float a0 = bias[tid], a1 = bias[tid], a2 = bias[tid], a3 = bias[tid];
    for (int k = 0; k < 1000; k += 4) {
      float w0 = W[(k + 0) * 300 + tid];
      float w1 = W[(k + 1) * 300 + tid];
      float w2 = W[(k + 2) * 300 + tid];
      float w3 = W[(k + 3) * 300 + tid];
      const float4 v0 = *(const float4*)(&es[0][k]);
      const float4 v1 = *(const float4*)(&es[1][k]);
      const float4 v2 = *(const float4*)(&es[2][k]);
      const float4 v3 = *(const float4*)(&es[3][k]);
      a0 += v0.x * w0 + v0.y * w1 + v0.z * w2 + v0.w * w3;
      a1 += v1.x * w0 + v1.y * w1 + v1.z * w2 + v1.w * w3;
      a2 += v2.x * w0 + v2.y * w1 + v2.z * w2 + v2.w * w3;
      a3 += v3.x * w0 + v3.y * w1 + v3.z * w2 + v3.w * w3;
    }
    small[(e0 + 0) * 300 + tid] = a0;
    small[(e0 + 1) * 300 + tid] = a1;
    small[(e0 + 2) * 300 + tid] = a2;
    small[(e0 + 3) * 300 + tid] = a3;
  }
}

// ---------------------------------------------------------------------------
__global__ __launch_bounds__(64) void k_renorm(
    const float* __restrict__ actors, float* __restrict__ actorsN) {
  const int a = blockIdx.x;
  const int l = threadIdx.x;
  float nsq = 0.f;
  for (int d = l; d < 300; d += 64) {
    float v = actors[a * 300 + d];
    nsq += v * v;
  }
  for (int off = 32; off; off >>= 1) nsq += __shfl_down(nsq, off);
  nsq = __shfl(nsq, 0);
  float sc = fminf(1.f, 1.f / fmaxf(sqrtf(nsq), 1e-7f));
  for (int d = l; d < 300; d += 64) actorsN[a * 300 + d] = actors[a * 300 + d] * sc;
}

// ---------------------------------------------------------------------------
__global__ __launch_bounds__(64) void k_lse(
    const float* __restrict__ link, float* __restrict__ out) {
  const int a = blockIdx.x;
  const int l = threadIdx.x;
  float v[8];
  float m = -1e30f;
#pragma unroll
  for (int i = 0; i < 8; ++i) {
    v[i] = link[a * 512 + l + i * 64];
    m = fmaxf(m, v[i]);
  }
  for (int off = 32; off; off >>= 1) m = fmaxf(m, __shfl_xor(m, off));
  float ssum = 0.f;
#pragma unroll
  for (int i = 0; i < 8; ++i) ssum += expf(v[i] - m);
  for (int off = 32; off; off >>= 1) ssum += __shfl_xor(ssum, off);
  if (l == 0) out[a] = logf(ssum) + m;
}

// ---------------------------------------------------------------------------
extern "C" void kernel_launch(void* const* d_in, const int* in_sizes, int n_in,
                              void* d_out, int out_size, void* d_ws, size_t ws_size,
                              hipStream_t stream) {
  const float* fast_text = (const float*)d_in[0];
  const float* actor_matrix = (const float*)d_in[1];
  const float* char_table = (const float*)d_in[2];
  const float* w3 = (const float*)d_in[3];
  const float* b3 = (const float*)d_in[4];
  const float* w4 = (const float*)d_in[5];
  const float* b4 = (const float*)d_in[6];
  const float* w5 = (const float*)d_in[7];
  const float* b5 = (const float*)d_in[8];
  const float* Wi_f = (const float*)d_in[9];
  const float* Wh_f = (const float*)d_in[10];
  const float* b_f = (const float*)d_in[11];
  const float* Wi_b = (const float*)d_in[12];
  const float* Wh_b = (const float*)d_in[13];
  const float* b_b = (const float*)d_in[14];
  const float* alpha_W1 = (const float*)d_in[15];
  const float* alpha_b1 = (const float*)d_in[16];
  const float* alpha_W2 = (const float*)d_in[17];
  const float* alpha_b2 = (const float*)d_in[18];
  const float* alpha_w_out = (const float*)d_in[19];
  const float* feat_table = (const float*)d_in[20];
  const float* affine_W = (const float*)d_in[21];
  const float* affine_b = (const float*)d_in[22];
  const int* word_ids = (const int*)d_in[23];
  const int* char_ids = (const int*)d_in[24];
  const int* espans = (const int*)d_in[25];

  float* ws = (float*)d_ws;
  float* lstm_in = ws;                 // 1024*450
  float* xpF = lstm_in + 460800;       // 1024*600
  float* xpB = xpF + 614400;           // 1024*600
  float* keys = xpB + 614400;          // 1024*300
  float* enc = keys + 307200;          // 512*1000
  float* small = enc + 512000;         // 512*300
  float* actN = small + 153600;        // 2000*300

  float* out = (float*)d_out;
  float* score_link = out + 2000;  // 2000 x 512

  k_token<<<1024, 64, 0, stream>>>(fast_text, char_table, w3, b3, w4, b4, w5, b5,
                                   word_ids, char_ids, lstm_in);
  gemm_nt<<<dim3(16, 10), 256, 0, stream>>>(lstm_in, Wi_f, b_f, xpF, 1024, 600, 450);
  gemm_nt<<<dim3(16, 10), 256, 0, stream>>>(lstm_in, Wi_b, b_b, xpB, 1024, 600, 450);
  k_lstm<<<2, 640, 0, stream>>>(xpF, xpB, Wh_f, Wh_b, keys);
  k_renorm<<<2000, 64, 0, stream>>>(actor_matrix, actN);
  k_span<<<512, 320, 0, stream>>>(keys, lstm_in, alpha_W1, alpha_b1, alpha_W2,
                                  alpha_b2, alpha_w_out, feat_table, espans, enc);
  k_affine<<<128, 320, 0, stream>>>(enc, affine_W, affine_b, small);
  gemm_nt<<<dim3(32, 8), 256, 0, stream>>>(actN, small, nullptr, score_link,
                                           2000, 512, 300);
  k_lse<<<2000, 64, 0, stream>>>(score_link, out);
}

// Round 6
// 1233.477 us; speedup vs baseline: 1.4103x; 1.4103x over previous
//
#include <hip/hip_runtime.h>
#include <math.h>

typedef _Float16 h2f __attribute__((ext_vector_type(2)));

__device__ __forceinline__ float fdot2f(h2f a, h2f b, float c) {
#if __has_builtin(__builtin_amdgcn_fdot2)
  return __builtin_amdgcn_fdot2(a, b, c, false);
#else
  return c + (float)a[0] * (float)b[0] + (float)a[1] * (float)b[1];
#endif
}

// DPP quad_perm cross-lane (VALU pipe, not LDS): CTRL=0xB1 -> lane^1,
// CTRL=0x4E -> lane^2 (within each group of 4 lanes).
template <int CTRL>
__device__ __forceinline__ float dpp_f(float x) {
  union { float f; int i; } u, r;
  u.f = x;
  r.i = __builtin_amdgcn_update_dpp(0, u.i, CTRL, 0xF, 0xF, false);
  return r.f;
}

__device__ __forceinline__ float sigf(float x) {
  return __builtin_amdgcn_rcpf(1.f + __expf(-x));
}
__device__ __forceinline__ float tanh_fast(float x) {
  return 2.f * __builtin_amdgcn_rcpf(1.f + __expf(-2.f * x)) - 1.f;
}

__device__ __forceinline__ int clampi(int v, int lo, int hi) {
  return v < lo ? lo : (v > hi ? hi : v);
}

// ---------------------------------------------------------------------------
// Kernel A: per-token: ft gather + char conv (3,4,5) -> lstm_in[1024][450]
// ---------------------------------------------------------------------------
__global__ __launch_bounds__(64) void k_token(
    const float* __restrict__ fast_text, const float* __restrict__ char_table,
    const float* __restrict__ w3, const float* __restrict__ b3,
    const float* __restrict__ w4, const float* __restrict__ b4,
    const float* __restrict__ w5, const float* __restrict__ b5,
    const int* __restrict__ word_ids, const int* __restrict__ char_ids,
    float* __restrict__ lstm_in) {
  const int t = blockIdx.x;
  const int tid = threadIdx.x;
  __shared__ float ce[16][16];  // ce[l][ci]
  for (int i = tid; i < 256; i += 64) {
    int l = i >> 4, ci = i & 15;
    ce[l][ci] = char_table[char_ids[t * 16 + l] * 16 + ci];
  }
  __syncthreads();
  const int wid = word_ids[t];
  for (int d = tid; d < 300; d += 64)
    lstm_in[t * 450 + d] = fast_text[wid * 300 + d];
  const int f = tid;
  if (f < 50) {
    {
      float acc[14];
#pragma unroll
      for (int p = 0; p < 14; ++p) acc[p] = 0.f;
      for (int ci = 0; ci < 16; ++ci) {
#pragma unroll
        for (int kk = 0; kk < 3; ++kk) {
          float wv = w3[(f * 16 + ci) * 3 + kk];
#pragma unroll
          for (int p = 0; p < 14; ++p) acc[p] += ce[p + kk][ci] * wv;
        }
      }
      float m = acc[0];
#pragma unroll
      for (int p = 1; p < 14; ++p) m = fmaxf(m, acc[p]);
      lstm_in[t * 450 + 300 + f] = fmaxf(0.f, m + b3[f]);
    }
    {
      float acc[13];
#pragma unroll
      for (int p = 0; p < 13; ++p) acc[p] = 0.f;
      for (int ci = 0; ci < 16; ++ci) {
#pragma unroll
        for (int kk = 0; kk < 4; ++kk) {
          float wv = w4[(f * 16 + ci) * 4 + kk];
#pragma unroll
          for (int p = 0; p < 13; ++p) acc[p] += ce[p + kk][ci] * wv;
        }
      }
      float m = acc[0];
#pragma unroll
      for (int p = 1; p < 13; ++p) m = fmaxf(m, acc[p]);
      lstm_in[t * 450 + 350 + f] = fmaxf(0.f, m + b4[f]);
    }
    {
      float acc[12];
#pragma unroll
      for (int p = 0; p < 12; ++p) acc[p] = 0.f;
      for (int ci = 0; ci < 16; ++ci) {
#pragma unroll
        for (int kk = 0; kk < 5; ++kk) {
          float wv = w5[(f * 16 + ci) * 5 + kk];
#pragma unroll
          for (int p = 0; p < 12; ++p) acc[p] += ce[p + kk][ci] * wv;
        }
      }
      float m = acc[0];
#pragma unroll
      for (int p = 1; p < 12; ++p) m = fmaxf(m, acc[p]);
      lstm_in[t * 450 + 400 + f] = fmaxf(0.f, m + b5[f]);
    }
  }
}

// ---------------------------------------------------------------------------
// Generic fp32 GEMM: C[M][N] = A[M][K] @ W[N][K]^T (+ bias[N] if non-null)
// ---------------------------------------------------------------------------
__global__ __launch_bounds__(256) void gemm_nt(
    const float* __restrict__ A, const float* __restrict__ W,
    const float* __restrict__ bias, float* __restrict__ C,
    int M, int N, int K) {
  __shared__ float As[16][64];
  __shared__ float Ws[16][64];
  const int tid = threadIdx.x;
  const int tx = tid & 15, ty = tid >> 4;
  const int r0 = blockIdx.x * 64, c0 = blockIdx.y * 64;
  float acc[4][4] = {};
  for (int k0 = 0; k0 < K; k0 += 16) {
    for (int i = tid; i < 1024; i += 256) {
      int rr = i >> 4, kk = i & 15;
      int r = r0 + rr, k = k0 + kk;
      As[kk][rr] = (r < M && k < K) ? A[r * K + k] : 0.f;
      int c = c0 + rr;
      Ws[kk][rr] = (c < N && k < K) ? W[c * K + k] : 0.f;
    }
    __syncthreads();
#pragma unroll
    for (int kk = 0; kk < 16; ++kk) {
      const float4 av = *(const float4*)(&As[kk][ty * 4]);
      const float4 wv = *(const float4*)(&Ws[kk][tx * 4]);
      float a[4] = {av.x, av.y, av.z, av.w};
      float w[4] = {wv.x, wv.y, wv.z, wv.w};
#pragma unroll
      for (int i = 0; i < 4; ++i)
#pragma unroll
        for (int j = 0; j < 4; ++j) acc[i][j] += a[i] * w[j];
    }
    __syncthreads();
  }
#pragma unroll
  for (int i = 0; i < 4; ++i) {
    int r = r0 + ty * 4 + i;
    if (r >= M) continue;
#pragma unroll
    for (int j = 0; j < 4; ++j) {
      int c = c0 + tx * 4 + j;
      if (c < N) C[r * N + c] = acc[i][j] + (bias ? bias[c] : 0.f);
    }
  }
}

// ---------------------------------------------------------------------------
// Kernel C: LSTM recurrence, one block per direction. Split-K4 layout:
// thread tid -> unit u = tid>>2, quarter g = tid&3. Each thread computes
// partials of ALL FOUR gate rows {j*150+u} over k-quarter g (h padded to
// 160 halfs so quarters are 16B-aligned: 5 ds_read_b128 per thread per step,
// vs 19 in the full-broadcast layout -> LDS instr/step 190 -> 50).
// Partials are completed with a 2-stage DPP quad_perm reduce (VALU pipe,
// not LDS). Thread g ends owning the full z of row g*150+u; nonlinearity
// per thread; gate exchange within the quad via DPP as before.
// waves_per_eu(3,3) keeps the 80 weight h2f regs resident (round-2/3
// lesson: default heuristic spills them at 8 waves/EU).
// ---------------------------------------------------------------------------
__attribute__((amdgpu_waves_per_eu(3, 3)))
__global__ __launch_bounds__(640) void k_lstm(
    const float* __restrict__ xprojF, const float* __restrict__ xprojB,
    const float* __restrict__ Wh_f, const float* __restrict__ Wh_b,
    float* __restrict__ keys) {
  const int dir = blockIdx.x;
  const float* __restrict__ xp = dir ? xprojB : xprojF;
  const float* __restrict__ Wh = dir ? Wh_b : Wh_f;
  const int tid = threadIdx.x;
  const int u = tid >> 2;   // hidden unit (valid < 150)
  const int g = tid & 3;    // k-quarter, and final gate row: 0=i 1=f 2=g 3=o
  const int row = g * 150 + u;
  const bool act = (tid < 600);

  __shared__ alignas(16) h2f hbuf[2][80];  // h packed f16: 150 + 10 zero pad

  // weights: 4 gate rows x 20 h2f covering k in [40g, 40g+40)
  h2f w[4][20];
  if (act) {
#pragma unroll
    for (int j = 0; j < 4; ++j) {
      const float* Wr = Wh + (j * 150 + u) * 150;
#pragma unroll
      for (int kk = 0; kk < 20; ++kk) {
        const int k = 40 * g + 2 * kk;
        float x0 = 0.f, x1 = 0.f;
        if (k < 150) {  // k even, so k<150 implies k+1<=149 valid
          const float2 p = *(const float2*)(Wr + k);
          x0 = p.x;
          x1 = p.y;
        }
        h2f v;
        v[0] = (_Float16)x0;
        v[1] = (_Float16)x1;
        w[j][kk] = v;
      }
    }
  }
  for (int i = tid; i < 160; i += 640) {
    h2f z;
    z[0] = (_Float16)0.f;
    z[1] = (_Float16)0.f;
    hbuf[i / 80][i % 80] = z;
  }
  float c = 0.f;
  float xv = act ? xp[(dir ? 1023 : 0) * 600 + row] : 0.f;
  __syncthreads();

  int cur = 0;
  for (int step = 0; step < 1024; ++step) {
    const int t = dir ? (1023 - step) : step;
    const int tn = dir ? (t > 0 ? t - 1 : 0) : (t < 1023 ? t + 1 : 1023);
    if (act) {
      // prefetch next step's xp (hidden under the dot chain)
      const float xv_next = xp[tn * 600 + row];
      // 5 x ds_read_b128 of this thread's k-quarter (4 distinct addresses
      // per wave, bank-disjoint across g)
      const float4* hv = (const float4*)hbuf[cur] + 5 * g;
      float a0 = 0.f, a1 = 0.f, a2 = 0.f, a3 = 0.f;
#pragma unroll
      for (int i = 0; i < 5; ++i) {
        float4 q = hv[i];
        const h2f* hh = (const h2f*)&q;
#pragma unroll
        for (int m = 0; m < 4; ++m) {
          a0 = fdot2f(w[0][4 * i + m], hh[m], a0);
          a1 = fdot2f(w[1][4 * i + m], hh[m], a1);
          a2 = fdot2f(w[2][4 * i + m], hh[m], a2);
          a3 = fdot2f(w[3][4 * i + m], hh[m], a3);
        }
      }
      // stage 1: sum quarters {g, g^1} for each row
      const float e0 = a0 + dpp_f<0xB1>(a0);
      const float e1 = a1 + dpp_f<0xB1>(a1);
      const float e2 = a2 + dpp_f<0xB1>(a2);
      const float e3 = a3 + dpp_f<0xB1>(a3);
      // select the two rows this thread can finish (bit0(row)==bit0(g))
      const float fa = (g & 1) ? e1 : e0;
      const float fb = (g & 1) ? e3 : e2;
      // stage 2: sum quarters {g^2, g^3}
      const float ga_ = fa + dpp_f<0x4E>(fa);
      const float gb_ = fb + dpp_f<0x4E>(fb);
      const float z = ((g & 2) ? gb_ : ga_) + xv;
      xv = xv_next;
      // nonlinearity: sigmoid for i,f,o; tanh for g
      const float zz = (g == 2) ? 2.f * z : z;
      const float s = sigf(zz);
      const float val = (g == 2) ? (2.f * s - 1.f) : s;
      // gate exchange within the quad (DPP)
      const float v1 = dpp_f<0xB1>(val);  // at g0: f
      const float gv = dpp_f<0x4E>(val);  // at g0: g
      const float ov = dpp_f<0x4E>(v1);   // at g0: o
      if (g == 0) {
        c = v1 * c + val * gv;
        const float h = ov * tanh_fast(c);
        keys[t * 300 + dir * 150 + u] = h;
        ((_Float16*)hbuf[cur ^ 1])[u] = (_Float16)h;
      }
    }
    cur ^= 1;
    __syncthreads();
  }
}

// ---------------------------------------------------------------------------
// Kernel D: span scorer -> enc[512][1000]
// ---------------------------------------------------------------------------
__global__ __launch_bounds__(320) void k_span(
    const float* __restrict__ keys, const float* __restrict__ lstm_in,
    const float* __restrict__ W1, const float* __restrict__ b1,
    const float* __restrict__ W2, const float* __restrict__ b2,
    const float* __restrict__ w_out, const float* __restrict__ feat_table,
    const int* __restrict__ espans, float* __restrict__ enc) {
  const int e = blockIdx.x;
  const int tid = threadIdx.x;
  const int s = espans[e * 4 + 0];
  const int en = espans[e * 4 + 1];
  const int f0 = espans[e * 4 + 2];
  const int f1 = espans[e * 4 + 3];

  __shared__ float ksh[10][300];
  __shared__ float hsh[10][152];
  __shared__ float h2sh[10][152];
  __shared__ float att[10];
  __shared__ float scl[2];

  for (int i = tid; i < 3000; i += 320) {
    int p = i / 300, d = i % 300;
    int row = clampi(s + p, 0, 1023);
    ksh[p][d] = keys[row * 300 + d];
  }
  __syncthreads();

  if (tid < 152) {
    int jj = tid;
    if (jj < 150) {
      float acc[10];
#pragma unroll
      for (int p = 0; p < 10; ++p) acc[p] = b1[jj];
      for (int k = 0; k < 300; k += 4) {
        float w0 = W1[(k + 0) * 150 + jj];
        float w1 = W1[(k + 1) * 150 + jj];
        float w2 = W1[(k + 2) * 150 + jj];
        float w3 = W1[(k + 3) * 150 + jj];
#pragma unroll
        for (int p = 0; p < 10; ++p) {
          const float4 kv = *(const float4*)(&ksh[p][k]);
          acc[p] += kv.x * w0 + kv.y * w1 + kv.z * w2 + kv.w * w3;
        }
      }
#pragma unroll
      for (int p = 0; p < 10; ++p) hsh[p][jj] = fmaxf(acc[p], 0.f);
    } else {
#pragma unroll
      for (int p = 0; p < 10; ++p) hsh[p][jj] = 0.f;
    }
  }
  __syncthreads();

  if (tid < 150) {
    int jj = tid;
    float acc[10];
#pragma unroll
    for (int p = 0; p < 10; ++p) acc[p] = b2[jj];
    for (int k = 0; k < 152; k += 4) {
      float w0 = (k + 0 < 150) ? W2[(k + 0) * 150 + jj] : 0.f;
      float w1 = (k + 1 < 150) ? W2[(k + 1) * 150 + jj] : 0.f;
      float w2 = (k + 2 < 150) ? W2[(k + 2) * 150 + jj] : 0.f;
      float w3 = (k + 3 < 150) ? W2[(k + 3) * 150 + jj] : 0.f;
#pragma unroll
      for (int p = 0; p < 10; ++p) {
        const float4 hv = *(const float4*)(&hsh[p][k]);
        acc[p] += hv.x * w0 + hv.y * w1 + hv.z * w2 + hv.w * w3;
      }
    }
#pragma unroll
    for (int p = 0; p < 10; ++p) h2sh[p][jj] = fmaxf(acc[p], 0.f);
  }
  __syncthreads();

  if (tid < 10) {
    float lg = -1e30f;
    if (tid < en - s) {
      float d = 0.f;
      for (int k = 0; k < 150; ++k) d += h2sh[tid][k] * w_out[k];
      lg = d;
    }
    att[tid] = lg;
  }
  if (tid >= 64 && tid < 66) {
    int r = tid - 64;
    int fi = (r == 0) ? f0 : f1;
    float nsq = 0.f;
    for (int k = 0; k < 50; ++k) {
      float v = feat_table[fi * 50 + k];
      nsq += v * v;
    }
    float n = sqrtf(nsq);
    scl[r] = fminf(1.f, 1.f / fmaxf(n, 1e-7f));
  }
  __syncthreads();

  if (tid == 0) {
    float m = -1e30f;
    for (int p = 0; p < 10; ++p) m = fmaxf(m, att[p]);
    float ex[10];
    float ssum = 0.f;
    for (int p = 0; p < 10; ++p) {
      ex[p] = expf(att[p] - m);
      ssum += ex[p];
    }
    for (int p = 0; p < 10; ++p) att[p] = ex[p] / ssum;
  }
  __syncthreads();

  if (tid < 300) {
    int d = tid;
    float xf = keys[s * 300 + d];
    float xl = keys[(en - 1) * 300 + d];
    float xh = 0.f;
#pragma unroll
    for (int p = 0; p < 10; ++p) {
      int row = clampi(s + p, 0, 1023);
      xh += att[p] * lstm_in[row * 450 + d];
    }
    enc[e * 1000 + d] = xf;
    enc[e * 1000 + 300 + d] = xl;
    enc[e * 1000 + 600 + d] = xh;
  }
  if (tid < 100) {
    int r = tid / 50, cc = tid % 50;
    int fi = (r == 0) ? f0 : f1;
    enc[e * 1000 + 900 + tid] = feat_table[fi * 50 + cc] * scl[r];
  }
}

// ---------------------------------------------------------------------------
// Kernel E: small = enc @ affine_W + affine_b   (4 spans per block)
// ---------------------------------------------------------------------------
__global__ __launch_bounds__(320) void k_affine(
    const float* __restrict__ enc, const float* __restrict__ W,
    const float* __restrict__ bias, float* __restrict__ small) {
  const int e0 = blockIdx.x * 4;
  const int tid = threadIdx.x;
  __shared__ float es[4][1000];
  for (int i = tid; i < 4000; i += 320) es[i / 1000][i % 1000] = enc[e0 * 1000 + i];
  __syncthreads();
  if (tid < 300) {
    float a0 = bias[tid], a1 = bias[tid], a2 = bias[tid], a3 = bias[tid];
    for (int k = 0; k < 1000; k += 4) {
      float w0 = W[(k + 0) * 300 + tid];
      float w1 = W[(k + 1) * 300 + tid];
      float w2 = W[(k + 2) * 300 + tid];
      float w3 = W[(k + 3) * 300 + tid];
      const float4 v0 = *(const float4*)(&es[0][k]);
      const float4 v1 = *(const float4*)(&es[1][k]);
      const float4 v2 = *(const float4*)(&es[2][k]);
      const float4 v3 = *(const float4*)(&es[3][k]);
      a0 += v0.x * w0 + v0.y * w1 + v0.z * w2 + v0.w * w3;
      a1 += v1.x * w0 + v1.y * w1 + v1.z * w2 + v1.w * w3;
      a2 += v2.x * w0 + v2.y * w1 + v2.z * w2 + v2.w * w3;
      a3 += v3.x * w0 + v3.y * w1 + v3.z * w2 + v3.w * w3;
    }
    small[(e0 + 0) * 300 + tid] = a0;
    small[(e0 + 1) * 300 + tid] = a1;
    small[(e0 + 2) * 300 + tid] = a2;
    small[(e0 + 3) * 300 + tid] = a3;
  }
}

// ---------------------------------------------------------------------------
__global__ __launch_bounds__(64) void k_renorm(
    const float* __restrict__ actors, float* __restrict__ actorsN) {
  const int a = blockIdx.x;
  const int l = threadIdx.x;
  float nsq = 0.f;
  for (int d = l; d < 300; d += 64) {
    float v = actors[a * 300 + d];
    nsq += v * v;
  }
  for (int off = 32; off; off >>= 1) nsq += __shfl_down(nsq, off);
  nsq = __shfl(nsq, 0);
  float sc = fminf(1.f, 1.f / fmaxf(sqrtf(nsq), 1e-7f));
  for (int d = l; d < 300; d += 64) actorsN[a * 300 + d] = actors[a * 300 + d] * sc;
}

// ---------------------------------------------------------------------------
__global__ __launch_bounds__(64) void k_lse(
    const float* __restrict__ link, float* __restrict__ out) {
  const int a = blockIdx.x;
  const int l = threadIdx.x;
  float v[8];
  float m = -1e30f;
#pragma unroll
  for (int i = 0; i < 8; ++i) {
    v[i] = link[a * 512 + l + i * 64];
    m = fmaxf(m, v[i]);
  }
  for (int off = 32; off; off >>= 1) m = fmaxf(m, __shfl_xor(m, off));
  float ssum = 0.f;
#pragma unroll
  for (int i = 0; i < 8; ++i) ssum += expf(v[i] - m);
  for (int off = 32; off; off >>= 1) ssum += __shfl_xor(ssum, off);
  if (l == 0) out[a] = logf(ssum) + m;
}

// ---------------------------------------------------------------------------
extern "C" void kernel_launch(void* const* d_in, const int* in_sizes, int n_in,
                              void* d_out, int out_size, void* d_ws, size_t ws_size,
                              hipStream_t stream) {
  const float* fast_text = (const float*)d_in[0];
  const float* actor_matrix = (const float*)d_in[1];
  const float* char_table = (const float*)d_in[2];
  const float* w3 = (const float*)d_in[3];
  const float* b3 = (const float*)d_in[4];
  const float* w4 = (const float*)d_in[5];
  const float* b4 = (const float*)d_in[6];
  const float* w5 = (const float*)d_in[7];
  const float* b5 = (const float*)d_in[8];
  const float* Wi_f = (const float*)d_in[9];
  const float* Wh_f = (const float*)d_in[10];
  const float* b_f = (const float*)d_in[11];
  const float* Wi_b = (const float*)d_in[12];
  const float* Wh_b = (const float*)d_in[13];
  const float* b_b = (const float*)d_in[14];
  const float* alpha_W1 = (const float*)d_in[15];
  const float* alpha_b1 = (const float*)d_in[16];
  const float* alpha_W2 = (const float*)d_in[17];
  const float* alpha_b2 = (const float*)d_in[18];
  const float* alpha_w_out = (const float*)d_in[19];
  const float* feat_table = (const float*)d_in[20];
  const float* affine_W = (const float*)d_in[21];
  const float* affine_b = (const float*)d_in[22];
  const int* word_ids = (const int*)d_in[23];
  const int* char_ids = (const int*)d_in[24];
  const int* espans = (const int*)d_in[25];

  float* ws = (float*)d_ws;
  float* lstm_in = ws;                 // 1024*450
  float* xpF = lstm_in + 460800;       // 1024*600
  float* xpB = xpF + 614400;           // 1024*600
  float* keys = xpB + 614400;          // 1024*300
  float* enc = keys + 307200;          // 512*1000
  float* small = enc + 512000;         // 512*300
  float* actN = small + 153600;        // 2000*300

  float* out = (float*)d_out;
  float* score_link = out + 2000;  // 2000 x 512

  k_token<<<1024, 64, 0, stream>>>(fast_text, char_table, w3, b3, w4, b4, w5, b5,
                                   word_ids, char_ids, lstm_in);
  gemm_nt<<<dim3(16, 10), 256, 0, stream>>>(lstm_in, Wi_f, b_f, xpF, 1024, 600, 450);
  gemm_nt<<<dim3(16, 10), 256, 0, stream>>>(lstm_in, Wi_b, b_b, xpB, 1024, 600, 450);
  k_lstm<<<2, 640, 0, stream>>>(xpF, xpB, Wh_f, Wh_b, keys);
  k_renorm<<<2000, 64, 0, stream>>>(actor_matrix, actN);
  k_span<<<512, 320, 0, stream>>>(keys, lstm_in, alpha_W1, alpha_b1, alpha_W2,
                                  alpha_b2, alpha_w_out, feat_table, espans, enc);
  k_affine<<<128, 320, 0, stream>>>(enc, affine_W, affine_b, small);
  gemm_nt<<<dim3(32, 8), 256, 0, stream>>>(actN, small, nullptr, score_link,
                                           2000, 512, 300);
  k_lse<<<2000, 64, 0, stream>>>(score_link, out);
}